// Round 8
// baseline (204.907 us; speedup 1.0000x reference)
//
#include <hip/hip_runtime.h>
#include <math.h>

// Problem constants (reference: B,D,E,H = 4,128,512,512)
#define BATCH 4
#define DDIM  128
#define EDIM  512
#define HDIM  512

// c = 2*log2(e): P=exp2(c*dec_t), Q=exp2(c*enc_t) so e^{2(dec+enc)} = P*Q
#define TANH_SCALE 2.8853900817779268f

typedef short short8v __attribute__((ext_vector_type(8)));
typedef float f32x4   __attribute__((ext_vector_type(4)));

#define EXP2F(x) __builtin_amdgcn_exp2f(x)
#define RCPF(x)  __builtin_amdgcn_rcpf(x)

// fp32 -> bf16 bits, round-to-nearest-even
static __device__ inline unsigned short f2bf(float f) {
    unsigned u = __float_as_uint(f);
    return (unsigned short)((u + 0x7FFFu + ((u >> 16) & 1u)) >> 16);
}
// pack two fp32 -> one u32 {bf16(f1):bf16(f0)}
static __device__ inline unsigned pack_bf2(float f0, float f1) {
    unsigned u0 = __float_as_uint(f0), u1 = __float_as_uint(f1);
    u0 += 0x7FFFu + ((u0 >> 16) & 1u);
    u1 += 0x7FFFu + ((u1 >> 16) & 1u);
    return __builtin_amdgcn_perm(u1, u0, 0x07060302u);
}
// bf16 bits -> fp32
static __device__ inline float bf2f(unsigned short h) {
    return __uint_as_float(((unsigned)h) << 16);
}

// ---------------------------------------------------------------------------
// bf16 MFMA GEMM pair (NT), epilogue bf16(exp2(c*acc)). 64x64 tile, BK=32,
// 256 threads = 4 waves (2m x 2n), wave tile 32x32 (2x2 frags of 16x16x32).
// 2-PHASE PIPELINE (T3-minimum): double-buffered LDS; next K-step's global
// loads are issued BEFORE the barrier; barrier is raw s_barrier preceded by
// lgkmcnt(0) ONLY (vmcnt stays outstanding across the barrier -> load
// latency hides under MFMA). One barrier per K-step: the pre-barrier
// lgkmcnt(0) completes each wave's ds_reads before it arrives, so the
// double-buffer WAR race is closed by the barrier itself.
//   blocks 0..63   : P[b,d,h] = exp2(c * sum_k xdec[b,d,k]*W2[h,k])
//   blocks 64..319 : Q[b,h,e] = exp2(c * sum_k W1[h,k]*xenc[b,e,k])
// Also zeroes the 256 attn pair-counters (block 0).
// ---------------------------------------------------------------------------
__global__ __launch_bounds__(256)
void gemm_both(const float* __restrict__ xdec, const float* __restrict__ W2,
               const float* __restrict__ xenc, const float* __restrict__ W1,
               unsigned short* __restrict__ P, unsigned short* __restrict__ Q,
               int* __restrict__ cnt) {
    if (blockIdx.x == 0 && threadIdx.x < 256) cnt[threadIdx.x] = 0;

    __shared__ unsigned short As[2][64][40];   // 10 KB (dbuf, 80B rows)
    __shared__ unsigned short Bs[2][64][40];   // 10 KB

    const int id = blockIdx.x;
    const float *Ab, *Bb;
    unsigned short* Cb;
    int m0, n0;
    if (id < 64) {                 // dec: 4b x 2m(d) x 8n(h)
        int b = id >> 4, r = id & 15;
        m0 = (r >> 3) * 64; n0 = (r & 7) * 64;
        Ab = xdec + (long)b * DDIM * HDIM;
        Bb = W2;
        Cb = P + (long)b * DDIM * HDIM;
    } else {                       // enc: 4b x 8m(h) x 8n(e)
        int t2 = id - 64;
        int b = t2 >> 6, r = t2 & 63;
        m0 = (r >> 3) * 64; n0 = (r & 7) * 64;
        Ab = W1;
        Bb = xenc + (long)b * EDIM * HDIM;
        Cb = Q + (long)b * HDIM * EDIM;
    }

    const int t    = threadIdx.x;
    const int srow = t >> 2;            // 0..63: staged row
    const int skq  = (t & 3) << 3;      // 0,8,16,24: k-offset (8 elems)

    const int wid = t >> 6, wm = wid >> 1, wn = wid & 1;
    const int l   = t & 63, lr = l & 15, c16 = l >> 4;

    f32x4 acc[2][2] = {};

    const float* ap = Ab + (long)(m0 + srow) * HDIM + skq;
    const float* bp = Bb + (long)(n0 + srow) * HDIM + skq;

    // prologue: load K-step 0
    float4 a0 = *(const float4*)ap, a1 = *(const float4*)(ap + 4);
    float4 b0 = *(const float4*)bp, b1 = *(const float4*)(bp + 4);

    int cur = 0;
    for (int k0 = 0; k0 < HDIM; k0 += 32) {
        // ---- pack current regs -> LDS[cur] ----
        uint4 apk, bpk;
        apk.x = pack_bf2(a0.x, a0.y); apk.y = pack_bf2(a0.z, a0.w);
        apk.z = pack_bf2(a1.x, a1.y); apk.w = pack_bf2(a1.z, a1.w);
        bpk.x = pack_bf2(b0.x, b0.y); bpk.y = pack_bf2(b0.z, b0.w);
        bpk.z = pack_bf2(b1.x, b1.y); bpk.w = pack_bf2(b1.z, b1.w);
        *(uint4*)&As[cur][srow][skq] = apk;
        *(uint4*)&Bs[cur][srow][skq] = bpk;

        // ---- issue next K-step's loads (stay in flight across barrier) ----
        if (k0 + 32 < HDIM) {
            ap += 32; bp += 32;
            a0 = *(const float4*)ap; a1 = *(const float4*)(ap + 4);
            b0 = *(const float4*)bp; b1 = *(const float4*)(bp + 4);
        }

        // ---- barrier: ds ops drained, vmcnt NOT drained ----
        asm volatile("s_waitcnt lgkmcnt(0)" ::: "memory");
        __builtin_amdgcn_s_barrier();
        __builtin_amdgcn_sched_barrier(0);

        // ---- fragments + MFMA from LDS[cur] ----
        short8v af[2], bf[2];
        #pragma unroll
        for (int fm = 0; fm < 2; ++fm)
            af[fm] = *(const short8v*)&As[cur][wm * 32 + fm * 16 + lr][c16 * 8];
        #pragma unroll
        for (int fn = 0; fn < 2; ++fn)
            bf[fn] = *(const short8v*)&Bs[cur][wn * 32 + fn * 16 + lr][c16 * 8];
        #pragma unroll
        for (int fm = 0; fm < 2; ++fm)
            #pragma unroll
            for (int fn = 0; fn < 2; ++fn)
                acc[fm][fn] = __builtin_amdgcn_mfma_f32_16x16x32_bf16(
                    af[fm], bf[fn], acc[fm][fn], 0, 0, 0);
        cur ^= 1;   // no second barrier: double buffer + pre-barrier lgkmcnt(0)
    }

    // epilogue: D[row=c16*4+r][col=lr] -> bf16(exp2(c*acc))
    const int crow = c16 << 2;
    #pragma unroll
    for (int fm = 0; fm < 2; ++fm)
        #pragma unroll
        for (int fn = 0; fn < 2; ++fn)
            #pragma unroll
            for (int r = 0; r < 4; ++r) {
                int rr = m0 + wm * 32 + fm * 16 + crow + r;
                int cc = n0 + wn * 32 + fn * 16 + lr;
                Cb[(long)rr * 512 + cc] = f2bf(EXP2F(TANH_SCALE * acc[fm][fn][r]));
            }
}

// ---------------------------------------------------------------------------
// Fused attn partial + last-block log_softmax finalize.
// 1024 blocks = 256 (b,d-pair) x 4 h-chunks -> 4 blocks/CU -> 8 waves/SIMD.
// Each block writes its f32 partials; the LAST chunk-block of a pair
// (atomic counter) re-reads all 4 slices and does masked log_softmax.
// Release/acquire via __threadfence + volatile reads (cross-XCD safe).
// partial layout: [pair][chunk][2 rows][512 e]
// ---------------------------------------------------------------------------
__global__ __launch_bounds__(512, 8)
void attn_fused(const unsigned short* __restrict__ P,  // (B,D,H) bf16 exp2
                const unsigned short* __restrict__ Q,  // (B,H,E) bf16 exp2
                const unsigned char* __restrict__ mask,// (B,E)
                const float* __restrict__ vw,          // (H)
                float* __restrict__ partial,
                int* __restrict__ cnt,
                float* __restrict__ out) {             // (B,D,E)
    const int g     = blockIdx.x;           // 0..1023
    const int xcd   = g & 7;
    const int b     = xcd & 3;
    const int idx   = g >> 3;               // 0..127
    const int chunk = idx & 3;              // 0..3
    const int dp    = (idx >> 2) + ((xcd >> 2) << 5);  // 0..63
    const int pair  = b * 64 + dp;          // 0..255
    const int bd0   = pair * 2;
    const int e     = threadIdx.x;          // 0..511
    const int h0    = chunk * 128;

    __shared__ float4 combo[128];           // {P0, P1, -2v, pad}
    __shared__ float  red0[8], red1[8];
    __shared__ int    amlast;

    if (e < 128) {
        int h = h0 + e;
        combo[e] = make_float4(bf2f(P[bd0 * HDIM + h]),
                               bf2f(P[(bd0 + 1) * HDIM + h]),
                               -2.0f * vw[h], 0.0f);
    }
    __syncthreads();

    const unsigned short* qb = Q + b * HDIM * EDIM + h0 * EDIM + e;
    float acc0 = 0.f, acc1 = 0.f;
    #pragma unroll 8
    for (int i = 0; i < 128; ++i) {
        float  q = bf2f(qb[i * EDIM]);
        float4 c = combo[i];
        acc0 = fmaf(c.z, RCPF(fmaf(c.x, q, 1.0f)), acc0);
        acc1 = fmaf(c.z, RCPF(fmaf(c.y, q, 1.0f)), acc1);
    }

    float* pp = partial + ((size_t)pair * 4 + chunk) * 1024;
    pp[e]       = acc0;
    pp[512 + e] = acc1;

    __threadfence();                        // release partials to device scope
    __syncthreads();
    if (e == 0)
        amlast = (atomicAdd(&cnt[pair], 1) == 3);
    __syncthreads();
    if (!amlast) return;

    // ---- last block of this pair: combine + masked log_softmax ----
    __threadfence();                        // acquire
    const volatile float* vp = partial + (size_t)pair * 4096;
    float v0 = (vp[e]       + vp[1024 + e]) + (vp[2048 + e] + vp[3072 + e]);
    float v1 = (vp[512 + e] + vp[1536 + e]) + (vp[2560 + e] + vp[3584 + e]);

    const bool mk = mask[b * EDIM + e];
    float val0 = mk ? -INFINITY : v0;
    float val1 = mk ? -INFINITY : v1;

    const int wid = e >> 6, lid = e & 63;

    float m0 = val0, m1 = val1;
    #pragma unroll
    for (int o = 32; o >= 1; o >>= 1) {
        m0 = fmaxf(m0, __shfl_xor(m0, o));
        m1 = fmaxf(m1, __shfl_xor(m1, o));
    }
    if (lid == 0) { red0[wid] = m0; red1[wid] = m1; }
    __syncthreads();
    m0 = red0[0]; m1 = red1[0];
    #pragma unroll
    for (int i = 1; i < 8; ++i) { m0 = fmaxf(m0, red0[i]); m1 = fmaxf(m1, red1[i]); }
    __syncthreads();

    float s0 = __expf(val0 - m0), s1 = __expf(val1 - m1);
    #pragma unroll
    for (int o = 32; o >= 1; o >>= 1) {
        s0 += __shfl_xor(s0, o);
        s1 += __shfl_xor(s1, o);
    }
    if (lid == 0) { red0[wid] = s0; red1[wid] = s1; }
    __syncthreads();
    float tot0 = 0.f, tot1 = 0.f;
    #pragma unroll
    for (int i = 0; i < 8; ++i) { tot0 += red0[i]; tot1 += red1[i]; }

    out[(long)bd0 * EDIM + e]       = val0 - m0 - __logf(tot0);
    out[(long)(bd0 + 1) * EDIM + e] = val1 - m1 - __logf(tot1);
}

// ---------------------------------------------------------------------------
extern "C" void kernel_launch(void* const* d_in, const int* in_sizes, int n_in,
                              void* d_out, int out_size, void* d_ws, size_t ws_size,
                              hipStream_t stream) {
    const float*         xdec = (const float*)d_in[0];         // (B,D,H)
    const float*         xenc = (const float*)d_in[1];         // (B,E,H)
    const unsigned char* mask = (const unsigned char*)d_in[2]; // (B,E)
    const float*         W1   = (const float*)d_in[3];         // (H,H)
    const float*         W2   = (const float*)d_in[4];         // (H,H)
    const float*         vw   = (const float*)d_in[5];         // (H)
    float*               out  = (float*)d_out;                 // (B,D,E)

    unsigned short* P = (unsigned short*)d_ws;                 // 262144 bf16
    unsigned short* Q = P + 262144;                            // 1048576 bf16
    float* partial    = (float*)(Q + 1048576);                 // 1048576 f32
    int*   cnt        = (int*)(partial + 1048576);             // 256 ints

    gemm_both<<<320, 256, 0, stream>>>(xdec, W2, xenc, W1, P, Q, cnt);
    attn_fused<<<1024, 512, 0, stream>>>(P, Q, mask, vw, partial, cnt, out);
}

// Round 9
// 37.082 us; speedup vs baseline: 5.5257x; 5.5257x over previous
//
#include <hip/hip_runtime.h>
#include <math.h>

// Problem constants (reference: B,D,E,H = 4,128,512,512)
#define BATCH 4
#define DDIM  128
#define EDIM  512
#define HDIM  512

// c = 2*log2(e): P=exp2(c*dec_t), Q=exp2(c*enc_t) so e^{2(dec+enc)} = P*Q
#define TANH_SCALE 2.8853900817779268f

typedef short short8v __attribute__((ext_vector_type(8)));
typedef float f32x4   __attribute__((ext_vector_type(4)));

#define EXP2F(x) __builtin_amdgcn_exp2f(x)
#define RCPF(x)  __builtin_amdgcn_rcpf(x)

// fp32 -> bf16 bits, round-to-nearest-even
static __device__ inline unsigned short f2bf(float f) {
    unsigned u = __float_as_uint(f);
    return (unsigned short)((u + 0x7FFFu + ((u >> 16) & 1u)) >> 16);
}
// pack two fp32 -> one u32 {bf16(f1):bf16(f0)}
static __device__ inline unsigned pack_bf2(float f0, float f1) {
    unsigned u0 = __float_as_uint(f0), u1 = __float_as_uint(f1);
    u0 += 0x7FFFu + ((u0 >> 16) & 1u);
    u1 += 0x7FFFu + ((u1 >> 16) & 1u);
    return __builtin_amdgcn_perm(u1, u0, 0x07060302u);
}
// bf16 bits -> fp32
static __device__ inline float bf2f(unsigned short h) {
    return __uint_as_float(((unsigned)h) << 16);
}

// ---------------------------------------------------------------------------
// bf16 MFMA GEMM pair (NT), epilogue bf16(exp2(c*acc)). 64x64 tile, BK=32,
// 256 threads = 4 waves (2m x 2n), wave tile 32x32 (2x2 frags of 16x16x32).
// 2-PHASE PIPELINE (measured ~6.5 us in R8 vs ~30 us for the barrier-drain
// structure): double-buffered LDS; next K-step's global loads issued BEFORE
// the barrier; raw s_barrier preceded by lgkmcnt(0) ONLY, so vmcnt stays
// outstanding across the barrier and HBM/L2 latency hides under MFMA.
// Single barrier per K-step is WAR-safe: each wave's ds_reads drain at its
// own pre-barrier lgkmcnt(0), and writes go to the opposite buffer.
//   blocks 0..63   : P[b,d,h] = exp2(c * sum_k xdec[b,d,k]*W2[h,k])
//   blocks 64..319 : Q[b,h,e] = exp2(c * sum_k W1[h,k]*xenc[b,e,k])
// ---------------------------------------------------------------------------
__global__ __launch_bounds__(256)
void gemm_both(const float* __restrict__ xdec, const float* __restrict__ W2,
               const float* __restrict__ xenc, const float* __restrict__ W1,
               unsigned short* __restrict__ P, unsigned short* __restrict__ Q) {
    __shared__ unsigned short As[2][64][40];   // 10 KB (dbuf, 80B rows)
    __shared__ unsigned short Bs[2][64][40];   // 10 KB

    const int id = blockIdx.x;
    const float *Ab, *Bb;
    unsigned short* Cb;
    int m0, n0;
    if (id < 64) {                 // dec: 4b x 2m(d) x 8n(h)
        int b = id >> 4, r = id & 15;
        m0 = (r >> 3) * 64; n0 = (r & 7) * 64;
        Ab = xdec + (long)b * DDIM * HDIM;
        Bb = W2;
        Cb = P + (long)b * DDIM * HDIM;
    } else {                       // enc: 4b x 8m(h) x 8n(e)
        int t2 = id - 64;
        int b = t2 >> 6, r = t2 & 63;
        m0 = (r >> 3) * 64; n0 = (r & 7) * 64;
        Ab = W1;
        Bb = xenc + (long)b * EDIM * HDIM;
        Cb = Q + (long)b * HDIM * EDIM;
    }

    const int t    = threadIdx.x;
    const int srow = t >> 2;            // 0..63: staged row
    const int skq  = (t & 3) << 3;      // 0,8,16,24: k-offset (8 elems)

    const int wid = t >> 6, wm = wid >> 1, wn = wid & 1;
    const int l   = t & 63, lr = l & 15, c16 = l >> 4;

    f32x4 acc[2][2] = {};

    const float* ap = Ab + (long)(m0 + srow) * HDIM + skq;
    const float* bp = Bb + (long)(n0 + srow) * HDIM + skq;

    // prologue: load K-step 0
    float4 a0 = *(const float4*)ap, a1 = *(const float4*)(ap + 4);
    float4 b0 = *(const float4*)bp, b1 = *(const float4*)(bp + 4);

    int cur = 0;
    for (int k0 = 0; k0 < HDIM; k0 += 32) {
        // ---- pack current regs -> LDS[cur] ----
        uint4 apk, bpk;
        apk.x = pack_bf2(a0.x, a0.y); apk.y = pack_bf2(a0.z, a0.w);
        apk.z = pack_bf2(a1.x, a1.y); apk.w = pack_bf2(a1.z, a1.w);
        bpk.x = pack_bf2(b0.x, b0.y); bpk.y = pack_bf2(b0.z, b0.w);
        bpk.z = pack_bf2(b1.x, b1.y); bpk.w = pack_bf2(b1.z, b1.w);
        *(uint4*)&As[cur][srow][skq] = apk;
        *(uint4*)&Bs[cur][srow][skq] = bpk;

        // ---- issue next K-step's loads (stay in flight across barrier) ----
        if (k0 + 32 < HDIM) {
            ap += 32; bp += 32;
            a0 = *(const float4*)ap; a1 = *(const float4*)(ap + 4);
            b0 = *(const float4*)bp; b1 = *(const float4*)(bp + 4);
        }

        // ---- barrier: ds ops drained, vmcnt NOT drained ----
        asm volatile("s_waitcnt lgkmcnt(0)" ::: "memory");
        __builtin_amdgcn_s_barrier();
        __builtin_amdgcn_sched_barrier(0);

        // ---- fragments + MFMA from LDS[cur] ----
        short8v af[2], bf[2];
        #pragma unroll
        for (int fm = 0; fm < 2; ++fm)
            af[fm] = *(const short8v*)&As[cur][wm * 32 + fm * 16 + lr][c16 * 8];
        #pragma unroll
        for (int fn = 0; fn < 2; ++fn)
            bf[fn] = *(const short8v*)&Bs[cur][wn * 32 + fn * 16 + lr][c16 * 8];
        #pragma unroll
        for (int fm = 0; fm < 2; ++fm)
            #pragma unroll
            for (int fn = 0; fn < 2; ++fn)
                acc[fm][fn] = __builtin_amdgcn_mfma_f32_16x16x32_bf16(
                    af[fm], bf[fn], acc[fm][fn], 0, 0, 0);
        cur ^= 1;
    }

    // epilogue: D[row=c16*4+r][col=lr] -> bf16(exp2(c*acc))
    const int crow = c16 << 2;
    #pragma unroll
    for (int fm = 0; fm < 2; ++fm)
        #pragma unroll
        for (int fn = 0; fn < 2; ++fn)
            #pragma unroll
            for (int r = 0; r < 4; ++r) {
                int rr = m0 + wm * 32 + fm * 16 + crow + r;
                int cc = n0 + wn * 32 + fn * 16 + lr;
                Cb[(long)rr * 512 + cc] = f2bf(EXP2F(TANH_SCALE * acc[fm][fn][r]));
            }
}

// ---------------------------------------------------------------------------
// Kernel A: partial tanh-dot (R7 version, fence-free). 1024 blocks =
// 256 (b,d-pair) x 4 h-chunks -> 4 blocks/CU -> 8 waves/SIMD.
// partial layout: [pair][chunk][2 rows][512 e]
// ---------------------------------------------------------------------------
__global__ __launch_bounds__(512)
void attn_partial(const unsigned short* __restrict__ P,  // (B,D,H) bf16 exp2
                  const unsigned short* __restrict__ Q,  // (B,H,E) bf16 exp2
                  const float* __restrict__ vw,          // (H)
                  float* __restrict__ partial) {
    const int g     = blockIdx.x;           // 0..1023
    const int xcd   = g & 7;
    const int b     = xcd & 3;
    const int idx   = g >> 3;               // 0..127
    const int chunk = idx & 3;              // 0..3
    const int dp    = (idx >> 2) + ((xcd >> 2) << 5);  // 0..63
    const int pair  = b * 64 + dp;          // 0..255
    const int bd0   = pair * 2;
    const int e     = threadIdx.x;          // 0..511
    const int h0    = chunk * 128;

    __shared__ float4 combo[128];           // {P0, P1, -2v, pad} (2 KB)
    if (e < 128) {
        int h = h0 + e;
        combo[e] = make_float4(bf2f(P[bd0 * HDIM + h]),
                               bf2f(P[(bd0 + 1) * HDIM + h]),
                               -2.0f * vw[h], 0.0f);
    }
    __syncthreads();

    const unsigned short* qb = Q + b * HDIM * EDIM + h0 * EDIM + e;
    float acc0 = 0.f, acc1 = 0.f;
    #pragma unroll 8
    for (int i = 0; i < 128; ++i) {
        float  q = bf2f(qb[i * EDIM]);
        float4 c = combo[i];
        acc0 = fmaf(c.z, RCPF(fmaf(c.x, q, 1.0f)), acc0);
        acc1 = fmaf(c.z, RCPF(fmaf(c.y, q, 1.0f)), acc1);
    }

    float* pp = partial + ((size_t)pair * 4 + chunk) * 1024;
    pp[e]       = acc0;
    pp[512 + e] = acc1;
}

// ---------------------------------------------------------------------------
// Kernel B: combine 4 partials + masked log_softmax + write out.
// 256 blocks x 512 threads; 16 KB read/block.
// ---------------------------------------------------------------------------
__global__ __launch_bounds__(512)
void lsm_final(const float* __restrict__ partial,
               const unsigned char* __restrict__ mask,  // (B,E)
               float* __restrict__ out) {               // (B,D,E)
    const int pair = blockIdx.x;       // 0..255 = b*64 + dp
    const int b    = pair >> 6;
    const int bd0  = pair * 2;
    const int e    = threadIdx.x;      // 0..511

    __shared__ float red0[8], red1[8];

    const float* pp = partial + (size_t)pair * 4096;
    float acc0 = (pp[e]        + pp[1024 + e]) + (pp[2048 + e] + pp[3072 + e]);
    float acc1 = (pp[512 + e]  + pp[1536 + e]) + (pp[2560 + e] + pp[3584 + e]);

    const bool mk = mask[b * EDIM + e];
    float val0 = mk ? -INFINITY : acc0;
    float val1 = mk ? -INFINITY : acc1;

    const int wid = e >> 6, lid = e & 63;

    // --- block max (both rows) ---
    float m0 = val0, m1 = val1;
    #pragma unroll
    for (int o = 32; o >= 1; o >>= 1) {
        m0 = fmaxf(m0, __shfl_xor(m0, o));
        m1 = fmaxf(m1, __shfl_xor(m1, o));
    }
    if (lid == 0) { red0[wid] = m0; red1[wid] = m1; }
    __syncthreads();
    m0 = red0[0]; m1 = red1[0];
    #pragma unroll
    for (int i = 1; i < 8; ++i) { m0 = fmaxf(m0, red0[i]); m1 = fmaxf(m1, red1[i]); }
    __syncthreads();

    // --- block sum of exp(val - m) ---
    float s0 = __expf(val0 - m0), s1 = __expf(val1 - m1);
    #pragma unroll
    for (int o = 32; o >= 1; o >>= 1) {
        s0 += __shfl_xor(s0, o);
        s1 += __shfl_xor(s1, o);
    }
    if (lid == 0) { red0[wid] = s0; red1[wid] = s1; }
    __syncthreads();
    float tot0 = 0.f, tot1 = 0.f;
    #pragma unroll
    for (int i = 0; i < 8; ++i) { tot0 += red0[i]; tot1 += red1[i]; }

    out[(long)bd0 * EDIM + e]       = val0 - m0 - __logf(tot0);
    out[(long)(bd0 + 1) * EDIM + e] = val1 - m1 - __logf(tot1);
}

// ---------------------------------------------------------------------------
extern "C" void kernel_launch(void* const* d_in, const int* in_sizes, int n_in,
                              void* d_out, int out_size, void* d_ws, size_t ws_size,
                              hipStream_t stream) {
    const float*         xdec = (const float*)d_in[0];         // (B,D,H)
    const float*         xenc = (const float*)d_in[1];         // (B,E,H)
    const unsigned char* mask = (const unsigned char*)d_in[2]; // (B,E)
    const float*         W1   = (const float*)d_in[3];         // (H,H)
    const float*         W2   = (const float*)d_in[4];         // (H,H)
    const float*         vw   = (const float*)d_in[5];         // (H)
    float*               out  = (float*)d_out;                 // (B,D,E)

    unsigned short* P = (unsigned short*)d_ws;                 // 262144 bf16 (512 KB)
    unsigned short* Q = P + 262144;                            // 1048576 bf16 (2 MB)
    float* partial    = (float*)(Q + 1048576);                 // 1048576 f32 (4 MB)

    gemm_both<<<320, 256, 0, stream>>>(xdec, W2, xenc, W1, P, Q);
    attn_partial<<<1024, 512, 0, stream>>>(P, Q, vw, partial);
    lsm_final<<<256, 512, 0, stream>>>(partial, mask, out);
}

// Round 10
// 35.924 us; speedup vs baseline: 5.7038x; 1.0322x over previous
//
#include <hip/hip_runtime.h>
#include <math.h>

// Problem constants (reference: B,D,E,H = 4,128,512,512)
#define BATCH 4
#define DDIM  128
#define EDIM  512
#define HDIM  512

// c = 2*log2(e): P=exp2(c*dec_t), Q=exp2(c*enc_t) so e^{2(dec+enc)} = P*Q
#define TANH_SCALE 2.8853900817779268f

typedef short short8v __attribute__((ext_vector_type(8)));
typedef float f32x4   __attribute__((ext_vector_type(4)));

#define EXP2F(x) __builtin_amdgcn_exp2f(x)
#define RCPF(x)  __builtin_amdgcn_rcpf(x)

// fp32 -> bf16 bits, round-to-nearest-even
static __device__ inline unsigned short f2bf(float f) {
    unsigned u = __float_as_uint(f);
    return (unsigned short)((u + 0x7FFFu + ((u >> 16) & 1u)) >> 16);
}
// pack two fp32 -> one u32 {bf16(f1):bf16(f0)}
static __device__ inline unsigned pack_bf2(float f0, float f1) {
    unsigned u0 = __float_as_uint(f0), u1 = __float_as_uint(f1);
    u0 += 0x7FFFu + ((u0 >> 16) & 1u);
    u1 += 0x7FFFu + ((u1 >> 16) & 1u);
    return __builtin_amdgcn_perm(u1, u0, 0x07060302u);
}
// bf16 bits -> fp32
static __device__ inline float bf2f(unsigned short h) {
    return __uint_as_float(((unsigned)h) << 16);
}

// ---------------------------------------------------------------------------
// bf16 MFMA GEMM pair (NT), 2-phase pipeline — UNCHANGED from R9 (~6.5 us
// measured via R8 timestamp bound).
//   blocks 0..63   : P[b,d,h] = exp2(c * sum_k xdec[b,d,k]*W2[h,k])
//   blocks 64..319 : Q[b,h,e] = exp2(c * sum_k W1[h,k]*xenc[b,e,k])
// ---------------------------------------------------------------------------
__global__ __launch_bounds__(256)
void gemm_both(const float* __restrict__ xdec, const float* __restrict__ W2,
               const float* __restrict__ xenc, const float* __restrict__ W1,
               unsigned short* __restrict__ P, unsigned short* __restrict__ Q) {
    __shared__ unsigned short As[2][64][40];   // 10 KB (dbuf, 80B rows)
    __shared__ unsigned short Bs[2][64][40];   // 10 KB

    const int id = blockIdx.x;
    const float *Ab, *Bb;
    unsigned short* Cb;
    int m0, n0;
    if (id < 64) {                 // dec: 4b x 2m(d) x 8n(h)
        int b = id >> 4, r = id & 15;
        m0 = (r >> 3) * 64; n0 = (r & 7) * 64;
        Ab = xdec + (long)b * DDIM * HDIM;
        Bb = W2;
        Cb = P + (long)b * DDIM * HDIM;
    } else {                       // enc: 4b x 8m(h) x 8n(e)
        int t2 = id - 64;
        int b = t2 >> 6, r = t2 & 63;
        m0 = (r >> 3) * 64; n0 = (r & 7) * 64;
        Ab = W1;
        Bb = xenc + (long)b * EDIM * HDIM;
        Cb = Q + (long)b * HDIM * EDIM;
    }

    const int t    = threadIdx.x;
    const int srow = t >> 2;            // 0..63: staged row
    const int skq  = (t & 3) << 3;      // 0,8,16,24: k-offset (8 elems)

    const int wid = t >> 6, wm = wid >> 1, wn = wid & 1;
    const int l   = t & 63, lr = l & 15, c16 = l >> 4;

    f32x4 acc[2][2] = {};

    const float* ap = Ab + (long)(m0 + srow) * HDIM + skq;
    const float* bp = Bb + (long)(n0 + srow) * HDIM + skq;

    // prologue: load K-step 0
    float4 a0 = *(const float4*)ap, a1 = *(const float4*)(ap + 4);
    float4 b0 = *(const float4*)bp, b1 = *(const float4*)(bp + 4);

    int cur = 0;
    for (int k0 = 0; k0 < HDIM; k0 += 32) {
        // ---- pack current regs -> LDS[cur] ----
        uint4 apk, bpk;
        apk.x = pack_bf2(a0.x, a0.y); apk.y = pack_bf2(a0.z, a0.w);
        apk.z = pack_bf2(a1.x, a1.y); apk.w = pack_bf2(a1.z, a1.w);
        bpk.x = pack_bf2(b0.x, b0.y); bpk.y = pack_bf2(b0.z, b0.w);
        bpk.z = pack_bf2(b1.x, b1.y); bpk.w = pack_bf2(b1.z, b1.w);
        *(uint4*)&As[cur][srow][skq] = apk;
        *(uint4*)&Bs[cur][srow][skq] = bpk;

        // ---- issue next K-step's loads (stay in flight across barrier) ----
        if (k0 + 32 < HDIM) {
            ap += 32; bp += 32;
            a0 = *(const float4*)ap; a1 = *(const float4*)(ap + 4);
            b0 = *(const float4*)bp; b1 = *(const float4*)(bp + 4);
        }

        // ---- barrier: ds ops drained, vmcnt NOT drained ----
        asm volatile("s_waitcnt lgkmcnt(0)" ::: "memory");
        __builtin_amdgcn_s_barrier();
        __builtin_amdgcn_sched_barrier(0);

        // ---- fragments + MFMA from LDS[cur] ----
        short8v af[2], bf[2];
        #pragma unroll
        for (int fm = 0; fm < 2; ++fm)
            af[fm] = *(const short8v*)&As[cur][wm * 32 + fm * 16 + lr][c16 * 8];
        #pragma unroll
        for (int fn = 0; fn < 2; ++fn)
            bf[fn] = *(const short8v*)&Bs[cur][wn * 32 + fn * 16 + lr][c16 * 8];
        #pragma unroll
        for (int fm = 0; fm < 2; ++fm)
            #pragma unroll
            for (int fn = 0; fn < 2; ++fn)
                acc[fm][fn] = __builtin_amdgcn_mfma_f32_16x16x32_bf16(
                    af[fm], bf[fn], acc[fm][fn], 0, 0, 0);
        cur ^= 1;
    }

    // epilogue: D[row=c16*4+r][col=lr] -> bf16(exp2(c*acc))
    const int crow = c16 << 2;
    #pragma unroll
    for (int fm = 0; fm < 2; ++fm)
        #pragma unroll
        for (int fn = 0; fn < 2; ++fn)
            #pragma unroll
            for (int r = 0; r < 4; ++r) {
                int rr = m0 + wm * 32 + fm * 16 + crow + r;
                int cc = n0 + wn * 32 + fn * 16 + lr;
                Cb[(long)rr * 512 + cc] = f2bf(EXP2F(TANH_SCALE * acc[fm][fn][r]));
            }
}

// ---------------------------------------------------------------------------
// Kernel A (v2): partial tanh-dot, VECTORIZED loads. 1024 blocks =
// 256 (b,d-pair) x 4 h-chunks; 512 threads = 128 e-quads x 4 h-subgroups.
// Each thread: 4 consecutive e via one uint2 (4xbf16, 8B) load per h,
// 32 h iterations -> 4x fewer load instructions than the scalar version.
// Subgroup partials reduced through LDS; output layout unchanged:
// partial[pair][chunk][2 rows][512 e].
// ---------------------------------------------------------------------------
__global__ __launch_bounds__(512)
void attn_partial(const unsigned short* __restrict__ P,  // (B,D,H) bf16 exp2
                  const unsigned short* __restrict__ Q,  // (B,H,E) bf16 exp2
                  const float* __restrict__ vw,          // (H)
                  float* __restrict__ partial) {
    const int g     = blockIdx.x;           // 0..1023
    const int xcd   = g & 7;
    const int b     = xcd & 3;
    const int idx   = g >> 3;               // 0..127
    const int chunk = idx & 3;              // 0..3
    const int dp    = (idx >> 2) + ((xcd >> 2) << 5);  // 0..63
    const int pair  = b * 64 + dp;          // 0..255
    const int bd0   = pair * 2;
    const int t     = threadIdx.x;          // 0..511
    const int eq    = t & 127;              // e-quad (4 e's each)
    const int hg    = t >> 7;               // h-subgroup 0..3 (32 h each)
    const int h0    = chunk * 128;

    __shared__ float4 combo[128];           // {P0, P1, -2v, pad} (2 KB)
    __shared__ float  lds[4][128][8];       // [hg][eq][d*4+ep]  (16 KB)

    if (t < 128) {
        int h = h0 + t;
        combo[t] = make_float4(bf2f(P[bd0 * HDIM + h]),
                               bf2f(P[(bd0 + 1) * HDIM + h]),
                               -2.0f * vw[h], 0.0f);
    }
    __syncthreads();

    const unsigned short* qb =
        Q + b * HDIM * EDIM + (h0 + hg * 32) * EDIM + eq * 4;
    float a00 = 0.f, a01 = 0.f, a02 = 0.f, a03 = 0.f;
    float a10 = 0.f, a11 = 0.f, a12 = 0.f, a13 = 0.f;
    #pragma unroll 8
    for (int ii = 0; ii < 32; ++ii) {
        uint2  qv = *(const uint2*)(qb + (size_t)ii * EDIM);
        float4 c  = combo[hg * 32 + ii];
        float q0 = __uint_as_float(qv.x << 16);
        float q1 = __uint_as_float(qv.x & 0xffff0000u);
        float q2 = __uint_as_float(qv.y << 16);
        float q3 = __uint_as_float(qv.y & 0xffff0000u);
        a00 = fmaf(c.z, RCPF(fmaf(c.x, q0, 1.0f)), a00);
        a01 = fmaf(c.z, RCPF(fmaf(c.x, q1, 1.0f)), a01);
        a02 = fmaf(c.z, RCPF(fmaf(c.x, q2, 1.0f)), a02);
        a03 = fmaf(c.z, RCPF(fmaf(c.x, q3, 1.0f)), a03);
        a10 = fmaf(c.z, RCPF(fmaf(c.y, q0, 1.0f)), a10);
        a11 = fmaf(c.z, RCPF(fmaf(c.y, q1, 1.0f)), a11);
        a12 = fmaf(c.z, RCPF(fmaf(c.y, q2, 1.0f)), a12);
        a13 = fmaf(c.z, RCPF(fmaf(c.y, q3, 1.0f)), a13);
    }

    float* myl = &lds[hg][eq][0];
    myl[0] = a00; myl[1] = a01; myl[2] = a02; myl[3] = a03;
    myl[4] = a10; myl[5] = a11; myl[6] = a12; myl[7] = a13;
    __syncthreads();

    // cross-subgroup reduce + write: thread t covers out positions t, t+512
    float* pp = partial + ((size_t)pair * 4 + chunk) * 1024;
    #pragma unroll
    for (int rep = 0; rep < 2; ++rep) {
        int pos = t + rep * 512;            // d*512 + e
        int d = pos >> 9, e = pos & 511;
        int j = d * 4 + (e & 3), eqi = e >> 2;
        float v = (lds[0][eqi][j] + lds[1][eqi][j]) +
                  (lds[2][eqi][j] + lds[3][eqi][j]);
        pp[pos] = v;
    }
}

// ---------------------------------------------------------------------------
// Kernel B: combine 4 partials + masked log_softmax + write out.
// UNCHANGED from R9.
// ---------------------------------------------------------------------------
__global__ __launch_bounds__(512)
void lsm_final(const float* __restrict__ partial,
               const unsigned char* __restrict__ mask,  // (B,E)
               float* __restrict__ out) {               // (B,D,E)
    const int pair = blockIdx.x;       // 0..255 = b*64 + dp
    const int b    = pair >> 6;
    const int bd0  = pair * 2;
    const int e    = threadIdx.x;      // 0..511

    __shared__ float red0[8], red1[8];

    const float* pp = partial + (size_t)pair * 4096;
    float acc0 = (pp[e]        + pp[1024 + e]) + (pp[2048 + e] + pp[3072 + e]);
    float acc1 = (pp[512 + e]  + pp[1536 + e]) + (pp[2560 + e] + pp[3584 + e]);

    const bool mk = mask[b * EDIM + e];
    float val0 = mk ? -INFINITY : acc0;
    float val1 = mk ? -INFINITY : acc1;

    const int wid = e >> 6, lid = e & 63;

    // --- block max (both rows) ---
    float m0 = val0, m1 = val1;
    #pragma unroll
    for (int o = 32; o >= 1; o >>= 1) {
        m0 = fmaxf(m0, __shfl_xor(m0, o));
        m1 = fmaxf(m1, __shfl_xor(m1, o));
    }
    if (lid == 0) { red0[wid] = m0; red1[wid] = m1; }
    __syncthreads();
    m0 = red0[0]; m1 = red1[0];
    #pragma unroll
    for (int i = 1; i < 8; ++i) { m0 = fmaxf(m0, red0[i]); m1 = fmaxf(m1, red1[i]); }
    __syncthreads();

    // --- block sum of exp(val - m) ---
    float s0 = __expf(val0 - m0), s1 = __expf(val1 - m1);
    #pragma unroll
    for (int o = 32; o >= 1; o >>= 1) {
        s0 += __shfl_xor(s0, o);
        s1 += __shfl_xor(s1, o);
    }
    if (lid == 0) { red0[wid] = s0; red1[wid] = s1; }
    __syncthreads();
    float tot0 = 0.f, tot1 = 0.f;
    #pragma unroll
    for (int i = 0; i < 8; ++i) { tot0 += red0[i]; tot1 += red1[i]; }

    out[(long)bd0 * EDIM + e]       = val0 - m0 - __logf(tot0);
    out[(long)(bd0 + 1) * EDIM + e] = val1 - m1 - __logf(tot1);
}

// ---------------------------------------------------------------------------
extern "C" void kernel_launch(void* const* d_in, const int* in_sizes, int n_in,
                              void* d_out, int out_size, void* d_ws, size_t ws_size,
                              hipStream_t stream) {
    const float*         xdec = (const float*)d_in[0];         // (B,D,H)
    const float*         xenc = (const float*)d_in[1];         // (B,E,H)
    const unsigned char* mask = (const unsigned char*)d_in[2]; // (B,E)
    const float*         W1   = (const float*)d_in[3];         // (H,H)
    const float*         W2   = (const float*)d_in[4];         // (H,H)
    const float*         vw   = (const float*)d_in[5];         // (H)
    float*               out  = (float*)d_out;                 // (B,D,E)

    unsigned short* P = (unsigned short*)d_ws;                 // 262144 bf16 (512 KB)
    unsigned short* Q = P + 262144;                            // 1048576 bf16 (2 MB)
    float* partial    = (float*)(Q + 1048576);                 // 1048576 f32 (4 MB)

    gemm_both<<<320, 256, 0, stream>>>(xdec, W2, xenc, W1, P, Q);
    attn_partial<<<1024, 512, 0, stream>>>(P, Q, vw, partial);
    lsm_final<<<256, 512, 0, stream>>>(partial, mask, out);
}